// Round 7
// baseline (246.748 us; speedup 1.0000x reference)
//
#include <hip/hip_runtime.h>
#include <cstdint>
#include <cstddef>

#define DEVI __device__ __forceinline__

typedef __bf16 bf16_t;
typedef __bf16 bf16x4 __attribute__((ext_vector_type(4)));
typedef __bf16 bf16x8 __attribute__((ext_vector_type(8)));
typedef short  s16x4  __attribute__((ext_vector_type(4)));
typedef float  f32x4  __attribute__((ext_vector_type(4)));
typedef unsigned short u16x4 __attribute__((ext_vector_type(4)));

static constexpr int Bz = 2, S = 2048, E = 1024, H = 16, Dh = 64;
static constexpr int M  = Bz * S;   // 4096 tokens
static constexpr int N  = H * Dh;   // 1024
static constexpr int Kd = E;        // 1024

DEVI unsigned short f2bf(float f) {
  unsigned u = __builtin_bit_cast(unsigned, f);
  return (unsigned short)((u + 0x7fffu + ((u >> 16) & 1u)) >> 16);
}

DEVI void async_copy16(void* lds, const void* g) {
  __builtin_amdgcn_global_load_lds((__attribute__((address_space(1))) void*)(g),
                                   (__attribute__((address_space(3))) void*)(lds), 16, 0, 0);
}

// 16x16x16 bf16 MFMA (K=16). B-frag layout B[k=quad*4+j][n=lane&15] matches the
// C-layout of a previous 16x16 MFMA register-for-register -> zero-cost P reuse.
DEVI f32x4 mfma16(bf16x4 a, bf16x4 b, f32x4 c) {
#if __has_builtin(__builtin_amdgcn_mfma_f32_16x16x16bf16_1k)
  return __builtin_amdgcn_mfma_f32_16x16x16bf16_1k(
      __builtin_bit_cast(s16x4, a), __builtin_bit_cast(s16x4, b), c, 0, 0, 0);
#elif __has_builtin(__builtin_amdgcn_mfma_f32_16x16x16_bf16)
  return __builtin_amdgcn_mfma_f32_16x16x16_bf16(a, b, c, 0, 0, 0);
#else
  asm("v_mfma_f32_16x16x16_bf16 %0, %1, %2, %0" : "+v"(c) : "v"(a), "v"(b));
  return c;
#endif
}

// ---------------- fused prep: convx | wtrans | rope table ----------------
__global__ void prep_kernel(const float* __restrict__ x, bf16_t* __restrict__ xb,
                            const float* __restrict__ Wq, const float* __restrict__ Wk,
                            const float* __restrict__ Wv, const float* __restrict__ Wo,
                            bf16_t* __restrict__ WtBase,
                            float* __restrict__ ropeC, float* __restrict__ ropeS) {
  __shared__ unsigned short tile[64][68];
  const int blk = blockIdx.x, tid = threadIdx.x;
  if (blk < 4096) {
    int i = blk * 256 + tid;
    float4 v = ((const float4*)x)[i];
    u16x4 o = { f2bf(v.x), f2bf(v.y), f2bf(v.z), f2bf(v.w) };
    ((u16x4*)xb)[i] = o;
  } else if (blk < 5120) {
    const int i = blk - 4096;
    const int z = i >> 8, rest = i & 255;
    const int n0 = (rest & 15) * 64, k0 = (rest >> 4) * 64;
    const float* W = (z == 0) ? Wq : (z == 1) ? Wk : (z == 2) ? Wv : Wo;
    unsigned short* T = (unsigned short*)(WtBase + (size_t)z * Kd * N);
    for (int e = tid; e < 1024; e += 256) {
      int r = e >> 4, c4 = (e & 15) * 4;
      float4 v = *(const float4*)(W + (size_t)(k0 + r) * N + n0 + c4);
      u16x4 o = { f2bf(v.x), f2bf(v.y), f2bf(v.z), f2bf(v.w) };
      *(u16x4*)&tile[r][c4] = o;
    }
    __syncthreads();
    for (int e = tid; e < 1024; e += 256) {
      int r = e >> 4, c4 = (e & 15) * 4;
      u16x4 o = { tile[c4][r], tile[c4 + 1][r], tile[c4 + 2][r], tile[c4 + 3][r] };
      *(u16x4*)&T[(size_t)(n0 + r) * Kd + k0 + c4] = o;
    }
  } else {
    int i = (blk - 5120) * 256 + tid;
    int pos = i >> 5, j = i & 31;
    float inv = exp2f(-(float)j * 0.41524101186092029f);   // log2(10000)/32
    float ang = (float)pos * inv;
    ropeC[i] = cosf(ang);
    ropeS[i] = sinf(ang);
  }
}

// ---------------- GEMM core (128x128 tile, BK=32, global_load_lds) ----------------

DEVI void gemm_mainloop(const bf16_t* __restrict__ A, const bf16_t* __restrict__ Bt,
                        bf16_t* sA, bf16_t* sB, int m0, int n0, f32x4 (&acc)[4][4]) {
  const int tid  = threadIdx.x;
  const int lane = tid & 63;
  const int wid  = tid >> 6;
  const int l16  = lane & 15;
  const int quad = lane >> 4;
  const int wm = (wid >> 1) * 64;
  const int wn = (wid & 1) * 64;
  const int o0 = wid * 2048 + lane * 16;   // byte offset within 8KB tile
  const int o1 = o0 + 1024;
  const int r0 = o0 >> 6, c0 = o0 & 63;
  const int r1 = o1 >> 6, c1 = o1 & 63;
  const char* Ab = (const char*)A;
  const char* Bb = (const char*)Bt;
  char* sAc = (char*)sA;
  char* sBc = (char*)sB;

  for (int k0 = 0; k0 < Kd; k0 += 32) {
    __syncthreads();
    async_copy16(sAc + wid * 2048,        Ab + ((size_t)(m0 + r0) * Kd + k0) * 2 + c0);
    async_copy16(sAc + wid * 2048 + 1024, Ab + ((size_t)(m0 + r1) * Kd + k0) * 2 + c1);
    async_copy16(sBc + wid * 2048,        Bb + ((size_t)(n0 + r0) * Kd + k0) * 2 + c0);
    async_copy16(sBc + wid * 2048 + 1024, Bb + ((size_t)(n0 + r1) * Kd + k0) * 2 + c1);
    __syncthreads();
    bf16x8 af[4], bfv[4];
#pragma unroll
    for (int mi = 0; mi < 4; ++mi)
      af[mi] = *(const bf16x8*)(sA + (wm + mi * 16 + l16) * 32 + quad * 8);
#pragma unroll
    for (int ni = 0; ni < 4; ++ni)
      bfv[ni] = *(const bf16x8*)(sB + (wn + ni * 16 + l16) * 32 + quad * 8);
#pragma unroll
    for (int mi = 0; mi < 4; ++mi)
#pragma unroll
      for (int ni = 0; ni < 4; ++ni)
        acc[mi][ni] = __builtin_amdgcn_mfma_f32_16x16x32_bf16(af[mi], bfv[ni], acc[mi][ni], 0, 0, 0);
  }
}

// z = 0:Q(RoPE+scale) 1:K(RoPE) -> [B,H,S,D]; z = 2:V -> TRANSPOSED [B,H,D,S]
__global__ __launch_bounds__(256, 3) void gemm_qkv_kernel(
    const bf16_t* __restrict__ xb, const bf16_t* __restrict__ WtBase,
    const float* __restrict__ bq, const float* __restrict__ bk, const float* __restrict__ bv,
    bf16_t* __restrict__ outBase, bf16_t* __restrict__ Vt,
    const float* __restrict__ ropeC, const float* __restrict__ ropeS) {
  __shared__ bf16_t sM[8192];               // mainloop: sA | sB ; epilogue: V^T tile
  const int z = blockIdx.z;
  const bf16_t* Bt = WtBase + (size_t)z * Kd * N;
  const float* bias = (z == 0) ? bq : (z == 1) ? bk : bv;
  const int n0 = blockIdx.x * 128, m0 = blockIdx.y * 128;
  f32x4 acc[4][4] = {};
  gemm_mainloop(xb, Bt, sM, sM + 4096, m0, n0, acc);

  const int tid = threadIdx.x, lane = tid & 63, wid = tid >> 6;
  const int l16 = lane & 15, quad = lane >> 4;
  const int wm = (wid >> 1) * 64, wn = (wid & 1) * 64;
  const int cbase = n0 + wn;          // 64-aligned -> one head per wave slab
  const int h = cbase >> 6;

  if (z < 2) {
    unsigned short* outp = (unsigned short*)(outBase + (size_t)z * M * N);
    // Q gets 0.125 (=1/sqrt(D)) * log2(e) folded in so attention can use exp2
    const float qs = (z == 0) ? 0.18033688011112042f : 1.0f;
#pragma unroll
    for (int mi = 0; mi < 4; ++mi)
#pragma unroll
      for (int r = 0; r < 4; ++r) {
        int t = m0 + wm + mi * 16 + quad * 4 + r;
        int bb = t >> 11, s = t & (S - 1);
        size_t obase = ((size_t)(bb * H + h) * S + s) * Dh;
#pragma unroll
        for (int np = 0; np < 2; ++np) {
          int j = np * 16 + l16;
          float cc = ropeC[s * 32 + j];
          float ss = ropeS[s * 32 + j];
          float xlo = acc[mi][np][r]     + bias[cbase + j];
          float xhi = acc[mi][np + 2][r] + bias[cbase + j + 32];
          outp[obase + j]      = f2bf((xlo * cc - xhi * ss) * qs);
          outp[obase + j + 32] = f2bf((xhi * cc + xlo * ss) * qs);
        }
      }
  } else {
    // fused V-transpose: acc -> LDS [dloc][t] (stride 136) -> coalesced Vt[B,H,D,S]
    const int bb = m0 >> 11, s0 = m0 & (S - 1);
    const int head0 = n0 >> 6;
    const int myh = wid & 1;             // this wave's head half (== wn/64)
    for (int hh = 0; hh < 2; ++hh)
      for (int dq = 0; dq < 2; ++dq) {
        __syncthreads();                 // LDS free / previous pass consumed
        if (myh == hh) {
#pragma unroll
          for (int ni2 = 0; ni2 < 2; ++ni2) {
            int ni = dq * 2 + ni2;
            int dloc = ni2 * 16 + l16;
            float bv_ = bias[cbase + ni * 16 + l16];
#pragma unroll
            for (int mi = 0; mi < 4; ++mi)
#pragma unroll
              for (int r = 0; r < 4; ++r) {
                int tloc = wm + mi * 16 + quad * 4 + r;
                sM[dloc * 136 + tloc] = (bf16_t)(acc[mi][ni][r] + bv_);
              }
          }
        }
        __syncthreads();
#pragma unroll
        for (int rep = 0; rep < 2; ++rep) {
          int cidx = rep * 256 + tid;    // 512 chunks of 16B = 32d x 128t
          int dloc = cidx >> 4, chunk = cidx & 15;
          bf16x8 v = *(const bf16x8*)&sM[dloc * 136 + chunk * 8];
          size_t off = ((size_t)(bb * H + head0 + hh) * Dh + dq * 32 + dloc) * S + s0 + chunk * 8;
          *(bf16x8*)(Vt + off) = v;
        }
      }
  }
}

// output GEMM: 64(m) x 128(n) tiles -> 512 blocks (2/CU)
__global__ __launch_bounds__(256, 4) void gemm_o_kernel(
    const bf16_t* __restrict__ A, const bf16_t* __restrict__ Bt,
    const float* __restrict__ bias, float* __restrict__ out) {
  __shared__ bf16_t sA[2048], sB[4096];     // 4KB A (64x32), 8KB B (128x32)
  const int n0 = blockIdx.x * 128, m0 = blockIdx.y * 64;
  const int tid = threadIdx.x, lane = tid & 63, wid = tid >> 6;
  const int l16 = lane & 15, quad = lane >> 4;
  const int wm = (wid >> 1) * 32, wn = (wid & 1) * 64;
  const int rowoff = lane >> 2, col8 = (lane & 3) * 8;
  const char* Ab = (const char*)A;
  const char* Bb = (const char*)Bt;
  char* sAc = (char*)sA;
  char* sBc = (char*)sB;
  f32x4 acc[2][4] = {};

  for (int k0 = 0; k0 < Kd; k0 += 32) {
    __syncthreads();
    async_copy16(sAc + wid * 1024,
                 Ab + ((size_t)(m0 + wid * 16 + rowoff) * Kd + k0 + col8) * 2);
    async_copy16(sBc + (wid * 2) * 1024,
                 Bb + ((size_t)(n0 + wid * 32 + rowoff) * Kd + k0 + col8) * 2);
    async_copy16(sBc + (wid * 2 + 1) * 1024,
                 Bb + ((size_t)(n0 + wid * 32 + 16 + rowoff) * Kd + k0 + col8) * 2);
    __syncthreads();
    bf16x8 af[2], bfv[4];
#pragma unroll
    for (int mi = 0; mi < 2; ++mi)
      af[mi] = *(const bf16x8*)(sA + (wm + mi * 16 + l16) * 32 + quad * 8);
#pragma unroll
    for (int ni = 0; ni < 4; ++ni)
      bfv[ni] = *(const bf16x8*)(sB + (wn + ni * 16 + l16) * 32 + quad * 8);
#pragma unroll
    for (int mi = 0; mi < 2; ++mi)
#pragma unroll
      for (int ni = 0; ni < 4; ++ni)
        acc[mi][ni] = __builtin_amdgcn_mfma_f32_16x16x32_bf16(af[mi], bfv[ni], acc[mi][ni], 0, 0, 0);
  }
#pragma unroll
  for (int mi = 0; mi < 2; ++mi)
#pragma unroll
    for (int r = 0; r < 4; ++r) {
      int t = m0 + wm + mi * 16 + quad * 4 + r;
#pragma unroll
      for (int ni = 0; ni < 4; ++ni) {
        int c = n0 + wn + ni * 16 + l16;
        out[(size_t)t * N + c] = acc[mi][ni][r] + bias[c];
      }
    }
}

// ---------------- flash attention (LDS-traffic-minimized) ----------------
// Block = 2 waves x 32 q = 64 q rows; 64-key LDS tiles (K 8KB + V 8KB) shared
// by the 2 waves. Each wave computes TWO 16-row q sub-tiles, halving LDS bytes
// read per q vs r3. QK uses 16x16x32 (S^T = K.Q^T, q per lane). PV uses
// 16x16x16: its B-frag layout equals the QK C-layout register-for-register, so
// P = exp2(S^T) feeds PV with ZERO transpose (no LDS P-bounce at all). V^T is
// read as 16x16x16 A-frags via ds_read_b64 from the staged tile. Fixed-m
// base-2 softmax (scale folded into Q); longest blocks launch first.
__global__ __launch_bounds__(128, 4) void attn_kernel(
    const bf16_t* __restrict__ Q, const bf16_t* __restrict__ Kb,
    const bf16_t* __restrict__ Vt, const int* __restrict__ mask,
    bf16_t* __restrict__ ctx) {
  __shared__ bf16_t sKV[8192];          // K tile elems [0,4096), V tile [4096,8192)

  const int tid = threadIdx.x, lane = tid & 63, wid = tid >> 6;   // wid 0/1
  const int l16 = lane & 15, quad = lane >> 4;

  const int idx = blockIdx.x;
  const int qb  = 31 - (idx >> 5);             // longest blocks launch first
  const int bh  = idx & 31;
  const int b   = bh >> 4;
  const int q0  = qb * 64;
  const int qw  = q0 + wid * 32;               // this wave's 32-q base

  const bf16_t* Qp = Q + ((size_t)bh * S + qw) * Dh;
  const char*   Kg = (const char*)(Kb + (size_t)bh * S * Dh);
  const char*   Vg = (const char*)(Vt + (size_t)bh * Dh * S);
  const int*    mp = mask + b * S;

  // Q as B-operand of 16x16x32 per 16-q sub-tile: B[k=d=ch*32+quad*8+j][n=q=l16]
  bf16x8 qf[2][2];
#pragma unroll
  for (int qs = 0; qs < 2; ++qs)
#pragma unroll
    for (int ch = 0; ch < 2; ++ch)
      qf[qs][ch] = *(const bf16x8*)(Qp + (qs * 16 + l16) * Dh + ch * 32 + quad * 8);

  // staging: wave wid fills K sections 4wid..4wid+3 and V sections 4wid..4wid+3.
  // K section (g,ch): elem(quad*16+l16)*8+t = K[kb+g*16+l16][ch*32+quad*8+t]
  // V section (dt,c): elem(quad*16+l16)*8+t = V^T[dt*16+l16][kb+c*32+quad*8+t]
  size_t kSrc[4], vSrc[4];
  int dstK[4], dstV[4];
#pragma unroll
  for (int i = 0; i < 4; ++i) {
    int sk = wid * 4 + i;
    kSrc[i] = ((size_t)((sk >> 1) * 16 + l16) * Dh + (sk & 1) * 32 + quad * 8) * 2;
    dstK[i] = sk * 1024;
    vSrc[i] = ((size_t)((sk >> 1) * 16 + l16) * S + (sk & 1) * 32 + quad * 8) * 2;
    dstV[i] = 8192 + sk * 1024;
  }
  char* sc = (char*)sKV;

  f32x4 acc[2][4] = {};
  float lsum[2] = { 0.f, 0.f };
  const int niter = qb + 1;

  for (int kt = 0; kt < niter; ++kt) {
    const int kb = kt * 64;
    __syncthreads();                           // previous tile fully consumed
#pragma unroll
    for (int i = 0; i < 4; ++i) {
      async_copy16(sc + dstK[i], Kg + (size_t)kb * 128 + kSrc[i]);
      async_copy16(sc + dstV[i], Vg + (size_t)kb * 2 + vSrc[i]);
    }
    int mk = mp[kb + lane];
    __syncthreads();                           // staging visible

    unsigned long long dm = __ballot(mk == 0);
    const bool last = (kt == niter - 1);

    // QK + mask + exp2 + pack, per 16-key group; P stays in registers as the
    // 16x16x16 B-frag (B[k=quad*4+j][n=l16] == C-layout of st).
    bf16x4 pf[2][4];
#pragma unroll
    for (int g = 0; g < 4; ++g) {
      bf16x8 kf0 = *(const bf16x8*)(sKV + (g * 2 + 0) * 512 + lane * 8);
      bf16x8 kf1 = *(const bf16x8*)(sKV + (g * 2 + 1) * 512 + lane * 8);
#pragma unroll
      for (int qs = 0; qs < 2; ++qs) {
        f32x4 z = {};
        z = __builtin_amdgcn_mfma_f32_16x16x32_bf16(kf0, qf[qs][0], z, 0, 0, 0);
        z = __builtin_amdgcn_mfma_f32_16x16x32_bf16(kf1, qf[qs][1], z, 0, 0, 0);
        if (dm) {
#pragma unroll
          for (int r = 0; r < 4; ++r)
            if ((dm >> (g * 16 + quad * 4 + r)) & 1ull) z[r] = -1e30f;
        }
        if (last) {
          int qcol = qw + qs * 16 + l16;
#pragma unroll
          for (int r = 0; r < 4; ++r)
            if (kb + g * 16 + quad * 4 + r > qcol) z[r] = -1e30f;
        }
        float e0 = exp2f(z[0]), e1 = exp2f(z[1]);
        float e2 = exp2f(z[2]), e3 = exp2f(z[3]);
        lsum[qs] += (e0 + e1) + (e2 + e3);
        pf[qs][g] = (bf16x4){ (bf16_t)e0, (bf16_t)e1, (bf16_t)e2, (bf16_t)e3 };
      }
    }

    // ctx^T += V^T.P^T via 16x16x16; A-frag of V^T chunk (dt, g):
    // lane(quad,l16) needs V^T[dt*16+l16][kb+g*16+quad*4+j], j=0..3 (b64 read)
#pragma unroll
    for (int dt = 0; dt < 4; ++dt)
#pragma unroll
      for (int g = 0; g < 4; ++g) {
        bf16x4 vf = *(const bf16x4*)(sKV + 4096 + (dt * 2 + (g >> 1)) * 512 +
                                     (((g & 1) * 2 + (quad >> 1)) * 16 + l16) * 8 +
                                     (quad & 1) * 4);
        acc[0][dt] = mfma16(vf, pf[0][g], acc[0][dt]);
        acc[1][dt] = mfma16(vf, pf[1][g], acc[1][dt]);
      }
  }

  asm volatile("s_nop 7\ns_nop 7" :::);        // MFMA->VALU read guard (asm path)
  unsigned short* cp = (unsigned short*)ctx;
#pragma unroll
  for (int qs = 0; qs < 2; ++qs) {
    float ls = lsum[qs];
    ls += __shfl_xor(ls, 16);
    ls += __shfl_xor(ls, 32);
    float inv = 1.0f / ls;
    size_t trow = ((size_t)(b * S + qw + qs * 16 + l16)) * N + (size_t)(bh & 15) * Dh;
#pragma unroll
    for (int dt = 0; dt < 4; ++dt) {
      u16x4 o = { f2bf(acc[qs][dt][0] * inv), f2bf(acc[qs][dt][1] * inv),
                  f2bf(acc[qs][dt][2] * inv), f2bf(acc[qs][dt][3] * inv) };
      *(u16x4*)&cp[trow + dt * 16 + quad * 4] = o;
    }
  }
}

// ---------------- launcher ----------------

extern "C" void kernel_launch(void* const* d_in, const int* in_sizes, int n_in,
                              void* d_out, int out_size, void* d_ws, size_t ws_size,
                              hipStream_t stream) {
  const float* x  = (const float*)d_in[0];
  const int*  msk = (const int*)d_in[1];
  const float* Wq = (const float*)d_in[2];
  const float* bq = (const float*)d_in[3];
  const float* Wk = (const float*)d_in[4];
  const float* bk = (const float*)d_in[5];
  const float* Wv = (const float*)d_in[6];
  const float* bv = (const float*)d_in[7];
  const float* Wo = (const float*)d_in[8];
  const float* bo = (const float*)d_in[9];
  float* out = (float*)d_out;
  (void)in_sizes; (void)n_in; (void)out_size; (void)ws_size;

  char* ws = (char*)d_ws;
  bf16_t* xb   = (bf16_t*)(ws);                      // 8 MB  [4096][1024]
  bf16_t* WT   = (bf16_t*)(ws + (8u  << 20));        // 8 MB  4 x [1024][1024] (N-major)
  bf16_t* Qb   = (bf16_t*)(ws + (16u << 20));        // 8 MB  [B,H,S,D]
  bf16_t* Kbuf = (bf16_t*)(ws + (24u << 20));        // 8 MB  [B,H,S,D]
  bf16_t* Vt   = (bf16_t*)(ws + (32u << 20));        // 8 MB  [B,H,D,S] (written by gemm_qkv z=2)
  float* ropeC = (float*)(ws + (40u << 20));         // 256 KB
  float* ropeS = ropeC + (size_t)S * 32;             // 256 KB
  bf16_t* ctx  = (bf16_t*)(ws + (41u << 20));        // 8 MB  [B,S,H*D]

  prep_kernel<<<5376, 256, 0, stream>>>(x, xb, Wq, Wk, Wv, Wo, WT, ropeC, ropeS);
  gemm_qkv_kernel<<<dim3(8, 32, 3), 256, 0, stream>>>(xb, WT, bq, bk, bv, Qb, Vt, ropeC, ropeS);
  attn_kernel<<<1024, 128, 0, stream>>>(Qb, Kbuf, Vt, msk, ctx);
  gemm_o_kernel<<<dim3(8, 64), 256, 0, stream>>>(ctx, WT + (size_t)3 * Kd * N, bo, out);
}

// Round 8
// 199.872 us; speedup vs baseline: 1.2345x; 1.2345x over previous
//
#include <hip/hip_runtime.h>
#include <cstdint>
#include <cstddef>

#define DEVI __device__ __forceinline__

typedef __bf16 bf16_t;
typedef __bf16 bf16x4 __attribute__((ext_vector_type(4)));
typedef __bf16 bf16x8 __attribute__((ext_vector_type(8)));
typedef float  f32x4  __attribute__((ext_vector_type(4)));
typedef unsigned short u16x4 __attribute__((ext_vector_type(4)));

static constexpr int Bz = 2, S = 2048, E = 1024, H = 16, Dh = 64;
static constexpr int M  = Bz * S;   // 4096 tokens
static constexpr int N  = H * Dh;   // 1024
static constexpr int Kd = E;        // 1024

DEVI unsigned short f2bf(float f) {
  unsigned u = __builtin_bit_cast(unsigned, f);
  return (unsigned short)((u + 0x7fffu + ((u >> 16) & 1u)) >> 16);
}

DEVI void async_copy16(void* lds, const void* g) {
  __builtin_amdgcn_global_load_lds((__attribute__((address_space(1))) void*)(g),
                                   (__attribute__((address_space(3))) void*)(lds), 16, 0, 0);
}

// ---------------- fused prep: convx | wtrans | rope table ----------------
__global__ void prep_kernel(const float* __restrict__ x, bf16_t* __restrict__ xb,
                            const float* __restrict__ Wq, const float* __restrict__ Wk,
                            const float* __restrict__ Wv, const float* __restrict__ Wo,
                            bf16_t* __restrict__ WtBase,
                            float* __restrict__ ropeC, float* __restrict__ ropeS) {
  __shared__ unsigned short tile[64][68];
  const int blk = blockIdx.x, tid = threadIdx.x;
  if (blk < 4096) {
    int i = blk * 256 + tid;
    float4 v = ((const float4*)x)[i];
    u16x4 o = { f2bf(v.x), f2bf(v.y), f2bf(v.z), f2bf(v.w) };
    ((u16x4*)xb)[i] = o;
  } else if (blk < 5120) {
    const int i = blk - 4096;
    const int z = i >> 8, rest = i & 255;
    const int n0 = (rest & 15) * 64, k0 = (rest >> 4) * 64;
    const float* W = (z == 0) ? Wq : (z == 1) ? Wk : (z == 2) ? Wv : Wo;
    unsigned short* T = (unsigned short*)(WtBase + (size_t)z * Kd * N);
    for (int e = tid; e < 1024; e += 256) {
      int r = e >> 4, c4 = (e & 15) * 4;
      float4 v = *(const float4*)(W + (size_t)(k0 + r) * N + n0 + c4);
      u16x4 o = { f2bf(v.x), f2bf(v.y), f2bf(v.z), f2bf(v.w) };
      *(u16x4*)&tile[r][c4] = o;
    }
    __syncthreads();
    for (int e = tid; e < 1024; e += 256) {
      int r = e >> 4, c4 = (e & 15) * 4;
      u16x4 o = { tile[c4][r], tile[c4 + 1][r], tile[c4 + 2][r], tile[c4 + 3][r] };
      *(u16x4*)&T[(size_t)(n0 + r) * Kd + k0 + c4] = o;
    }
  } else {
    int i = (blk - 5120) * 256 + tid;
    int pos = i >> 5, j = i & 31;
    float inv = exp2f(-(float)j * 0.41524101186092029f);   // log2(10000)/32
    float ang = (float)pos * inv;
    ropeC[i] = cosf(ang);
    ropeS[i] = sinf(ang);
  }
}

// ---------------- GEMM core (128x128 tile, BK=32, global_load_lds) ----------------

DEVI void gemm_mainloop(const bf16_t* __restrict__ A, const bf16_t* __restrict__ Bt,
                        bf16_t* sA, bf16_t* sB, int m0, int n0, f32x4 (&acc)[4][4]) {
  const int tid  = threadIdx.x;
  const int lane = tid & 63;
  const int wid  = tid >> 6;
  const int l16  = lane & 15;
  const int quad = lane >> 4;
  const int wm = (wid >> 1) * 64;
  const int wn = (wid & 1) * 64;
  const int o0 = wid * 2048 + lane * 16;   // byte offset within 8KB tile
  const int o1 = o0 + 1024;
  const int r0 = o0 >> 6, c0 = o0 & 63;
  const int r1 = o1 >> 6, c1 = o1 & 63;
  const char* Ab = (const char*)A;
  const char* Bb = (const char*)Bt;
  char* sAc = (char*)sA;
  char* sBc = (char*)sB;

  for (int k0 = 0; k0 < Kd; k0 += 32) {
    __syncthreads();
    async_copy16(sAc + wid * 2048,        Ab + ((size_t)(m0 + r0) * Kd + k0) * 2 + c0);
    async_copy16(sAc + wid * 2048 + 1024, Ab + ((size_t)(m0 + r1) * Kd + k0) * 2 + c1);
    async_copy16(sBc + wid * 2048,        Bb + ((size_t)(n0 + r0) * Kd + k0) * 2 + c0);
    async_copy16(sBc + wid * 2048 + 1024, Bb + ((size_t)(n0 + r1) * Kd + k0) * 2 + c1);
    __syncthreads();
    bf16x8 af[4], bfv[4];
#pragma unroll
    for (int mi = 0; mi < 4; ++mi)
      af[mi] = *(const bf16x8*)(sA + (wm + mi * 16 + l16) * 32 + quad * 8);
#pragma unroll
    for (int ni = 0; ni < 4; ++ni)
      bfv[ni] = *(const bf16x8*)(sB + (wn + ni * 16 + l16) * 32 + quad * 8);
#pragma unroll
    for (int mi = 0; mi < 4; ++mi)
#pragma unroll
      for (int ni = 0; ni < 4; ++ni)
        acc[mi][ni] = __builtin_amdgcn_mfma_f32_16x16x32_bf16(af[mi], bfv[ni], acc[mi][ni], 0, 0, 0);
  }
}

// z = 0:Q(RoPE+scale) 1:K(RoPE) -> [B,H,S,D]; z = 2:V -> TRANSPOSED [B,H,D,S]
__global__ __launch_bounds__(256, 3) void gemm_qkv_kernel(
    const bf16_t* __restrict__ xb, const bf16_t* __restrict__ WtBase,
    const float* __restrict__ bq, const float* __restrict__ bk, const float* __restrict__ bv,
    bf16_t* __restrict__ outBase, bf16_t* __restrict__ Vt,
    const float* __restrict__ ropeC, const float* __restrict__ ropeS) {
  __shared__ bf16_t sM[8192];               // mainloop: sA | sB ; epilogue: V^T tile
  const int z = blockIdx.z;
  const bf16_t* Bt = WtBase + (size_t)z * Kd * N;
  const float* bias = (z == 0) ? bq : (z == 1) ? bk : bv;
  const int n0 = blockIdx.x * 128, m0 = blockIdx.y * 128;
  f32x4 acc[4][4] = {};
  gemm_mainloop(xb, Bt, sM, sM + 4096, m0, n0, acc);

  const int tid = threadIdx.x, lane = tid & 63, wid = tid >> 6;
  const int l16 = lane & 15, quad = lane >> 4;
  const int wm = (wid >> 1) * 64, wn = (wid & 1) * 64;
  const int cbase = n0 + wn;          // 64-aligned -> one head per wave slab
  const int h = cbase >> 6;

  if (z < 2) {
    unsigned short* outp = (unsigned short*)(outBase + (size_t)z * M * N);
    // Q gets 0.125 (=1/sqrt(D)) * log2(e) folded in so attention can use exp2
    const float qs = (z == 0) ? 0.18033688011112042f : 1.0f;
#pragma unroll
    for (int mi = 0; mi < 4; ++mi)
#pragma unroll
      for (int r = 0; r < 4; ++r) {
        int t = m0 + wm + mi * 16 + quad * 4 + r;
        int bb = t >> 11, s = t & (S - 1);
        size_t obase = ((size_t)(bb * H + h) * S + s) * Dh;
#pragma unroll
        for (int np = 0; np < 2; ++np) {
          int j = np * 16 + l16;
          float cc = ropeC[s * 32 + j];
          float ss = ropeS[s * 32 + j];
          float xlo = acc[mi][np][r]     + bias[cbase + j];
          float xhi = acc[mi][np + 2][r] + bias[cbase + j + 32];
          outp[obase + j]      = f2bf((xlo * cc - xhi * ss) * qs);
          outp[obase + j + 32] = f2bf((xhi * cc + xlo * ss) * qs);
        }
      }
  } else {
    // fused V-transpose: acc -> LDS [dloc][t] (stride 136) -> coalesced Vt[B,H,D,S]
    const int bb = m0 >> 11, s0 = m0 & (S - 1);
    const int head0 = n0 >> 6;
    const int myh = wid & 1;             // this wave's head half (== wn/64)
    for (int hh = 0; hh < 2; ++hh)
      for (int dq = 0; dq < 2; ++dq) {
        __syncthreads();                 // LDS free / previous pass consumed
        if (myh == hh) {
#pragma unroll
          for (int ni2 = 0; ni2 < 2; ++ni2) {
            int ni = dq * 2 + ni2;
            int dloc = ni2 * 16 + l16;
            float bv_ = bias[cbase + ni * 16 + l16];
#pragma unroll
            for (int mi = 0; mi < 4; ++mi)
#pragma unroll
              for (int r = 0; r < 4; ++r) {
                int tloc = wm + mi * 16 + quad * 4 + r;
                sM[dloc * 136 + tloc] = (bf16_t)(acc[mi][ni][r] + bv_);
              }
          }
        }
        __syncthreads();
#pragma unroll
        for (int rep = 0; rep < 2; ++rep) {
          int cidx = rep * 256 + tid;    // 512 chunks of 16B = 32d x 128t
          int dloc = cidx >> 4, chunk = cidx & 15;
          bf16x8 v = *(const bf16x8*)&sM[dloc * 136 + chunk * 8];
          size_t off = ((size_t)(bb * H + head0 + hh) * Dh + dq * 32 + dloc) * S + s0 + chunk * 8;
          *(bf16x8*)(Vt + off) = v;
        }
      }
  }
}

// output GEMM: 64(m) x 128(n) tiles -> 512 blocks (2/CU)
__global__ __launch_bounds__(256, 4) void gemm_o_kernel(
    const bf16_t* __restrict__ A, const bf16_t* __restrict__ Bt,
    const float* __restrict__ bias, float* __restrict__ out) {
  __shared__ bf16_t sA[2048], sB[4096];     // 4KB A (64x32), 8KB B (128x32)
  const int n0 = blockIdx.x * 128, m0 = blockIdx.y * 64;
  const int tid = threadIdx.x, lane = tid & 63, wid = tid >> 6;
  const int l16 = lane & 15, quad = lane >> 4;
  const int wm = (wid >> 1) * 32, wn = (wid & 1) * 64;
  const int rowoff = lane >> 2, col8 = (lane & 3) * 8;
  const char* Ab = (const char*)A;
  const char* Bb = (const char*)Bt;
  char* sAc = (char*)sA;
  char* sBc = (char*)sB;
  f32x4 acc[2][4] = {};

  for (int k0 = 0; k0 < Kd; k0 += 32) {
    __syncthreads();
    async_copy16(sAc + wid * 1024,
                 Ab + ((size_t)(m0 + wid * 16 + rowoff) * Kd + k0 + col8) * 2);
    async_copy16(sBc + (wid * 2) * 1024,
                 Bb + ((size_t)(n0 + wid * 32 + rowoff) * Kd + k0 + col8) * 2);
    async_copy16(sBc + (wid * 2 + 1) * 1024,
                 Bb + ((size_t)(n0 + wid * 32 + 16 + rowoff) * Kd + k0 + col8) * 2);
    __syncthreads();
    bf16x8 af[2], bfv[4];
#pragma unroll
    for (int mi = 0; mi < 2; ++mi)
      af[mi] = *(const bf16x8*)(sA + (wm + mi * 16 + l16) * 32 + quad * 8);
#pragma unroll
    for (int ni = 0; ni < 4; ++ni)
      bfv[ni] = *(const bf16x8*)(sB + (wn + ni * 16 + l16) * 32 + quad * 8);
#pragma unroll
    for (int mi = 0; mi < 2; ++mi)
#pragma unroll
      for (int ni = 0; ni < 4; ++ni)
        acc[mi][ni] = __builtin_amdgcn_mfma_f32_16x16x32_bf16(af[mi], bfv[ni], acc[mi][ni], 0, 0, 0);
  }
#pragma unroll
  for (int mi = 0; mi < 2; ++mi)
#pragma unroll
    for (int r = 0; r < 4; ++r) {
      int t = m0 + wm + mi * 16 + quad * 4 + r;
#pragma unroll
      for (int ni = 0; ni < 4; ++ni) {
        int c = n0 + wn + ni * 16 + l16;
        out[(size_t)t * N + c] = acc[mi][ni][r] + bias[c];
      }
    }
}

// ---------------- flash attention: r3 skeleton + 32q/wave + key-split ----------------
// 4 waves x 256 thr, 1024 blocks (longest-first), 128-key tiles staged in
// 16x16x32-fragment order (all reads ds_read_b128 conflict-free), 2 barriers
// per iteration — exactly r3's proven structure. New decomposition: wave wid
// owns q-range (wid&1)*32 (two 16-q sub-tiles) and key-half (wid>>1)*64 of the
// tile, so LDS read bytes per q*k drop 2.1x vs r3 (each tile read serves 2x
// the q and each wave reads only half the tile). Fixed-m softmax makes the two
// key-half partials pure sums -> one LDS combine at the end. Waves whose key
// window is beyond their causal diagonal skip compute (still stage+barrier).
__global__ __launch_bounds__(256, 3) void attn_kernel(
    const bf16_t* __restrict__ Q, const bf16_t* __restrict__ Kb,
    const bf16_t* __restrict__ Vt, const int* __restrict__ mask,
    bf16_t* __restrict__ ctx) {
  __shared__ bf16_t sK[8192];                  // 128k x 64d, 16 sections (g*2+ch)*512
  __shared__ bf16_t sV[8192];                  // V^T 64d x 128k, 16 sections (dt*4+c)*512
  __shared__ unsigned short sP[4][2][16 * 72]; // [wave][qsub][ P[q=l16][key] stride 72 ]

  const int tid = threadIdx.x, lane = tid & 63, wid = tid >> 6;
  const int l16 = lane & 15, quad = lane >> 4;

  const int idx  = blockIdx.x;
  const int qblk = 31 - (idx >> 5);            // longest blocks launch first
  const int bh   = idx & 31;
  const int b    = bh >> 4;
  const int q0   = qblk * 64;
  const int qhalf = wid & 1, khalf = wid >> 1;
  const int qw   = q0 + qhalf * 32;            // this wave's 32-q base

  const bf16_t* Qp = Q + ((size_t)bh * S + qw) * Dh;
  const char*   Kg = (const char*)(Kb + (size_t)bh * S * Dh);
  const char*   Vg = (const char*)(Vt + (size_t)bh * Dh * S);
  const int*    mp = mask + b * S;

  // Q as B-operand of 16x16x32 per sub-tile: B[k=d=ch*32+quad*8+j][n=q=l16]
  bf16x8 qf[2][2];
#pragma unroll
  for (int qs = 0; qs < 2; ++qs)
#pragma unroll
    for (int ch = 0; ch < 2; ++ch)
      qf[qs][ch] = *(const bf16x8*)(Qp + (qs * 16 + l16) * Dh + ch * 32 + quad * 8);

  // staging: wave stages K sections wid*4..wid*4+3 and V sections wid*4..wid*4+3
  // K section s (g=s>>1, ch=s&1): lane l -> K[kb+g*16+l16][ch*32+quad*8+j]
  // V section s (dt=s>>2, c=s&3): lane l -> V^T[dt*16+l16][kb+c*32+quad*8+j]
  size_t kSrc[4], vSrc[4];
  int dstOff[4];
#pragma unroll
  for (int i = 0; i < 4; ++i) {
    int sk = wid * 4 + i;
    kSrc[i] = (((size_t)((sk >> 1) * 16 + l16)) * Dh + (sk & 1) * 32 + quad * 8) * 2;
    vSrc[i] = (((size_t)((sk >> 2) * 16 + l16)) * S + (sk & 3) * 32 + quad * 8) * 2;
    dstOff[i] = sk * 1024;
  }
  char* sKc = (char*)sK;
  char* sVc = (char*)sV;

  f32x4 acc[2][4] = {};
  float lsum[2] = { 0.f, 0.f };
  const int niter = (qblk >> 1) + 1;
  const int kwoff = khalf * 64;

  for (int kt = 0; kt < niter; ++kt) {
    const int kb = kt * 128;
    __syncthreads();                           // previous tile fully consumed
    int mk = mp[kb + kwoff + lane];            // before staging: no queue drain
#pragma unroll
    for (int i = 0; i < 4; ++i) {
      async_copy16(sKc + dstOff[i], Kg + (size_t)kb * 128 + kSrc[i]);
      async_copy16(sVc + dstOff[i], Vg + (size_t)kb * 2 + vSrc[i]);
    }
    __syncthreads();                           // staging visible
    const int kw = kb + kwoff;
    if (kw <= qw + 31) {                       // wave-uniform causal skip
      unsigned long long dm = __ballot(mk == 0);
      const bool causal = (kw + 63 > qw);

      // S^T = K.Q^T over this wave's 64-key window (4 groups of 16)
#pragma unroll
      for (int gl = 0; gl < 4; ++gl) {
        const bf16_t* ks = sK + (khalf * 8 + gl * 2) * 512 + lane * 8;
        bf16x8 kf0 = *(const bf16x8*)(ks);
        bf16x8 kf1 = *(const bf16x8*)(ks + 512);
#pragma unroll
        for (int qs = 0; qs < 2; ++qs) {
          f32x4 z = {};
          z = __builtin_amdgcn_mfma_f32_16x16x32_bf16(kf0, qf[qs][0], z, 0, 0, 0);
          z = __builtin_amdgcn_mfma_f32_16x16x32_bf16(kf1, qf[qs][1], z, 0, 0, 0);
          if (dm) {
#pragma unroll
            for (int r = 0; r < 4; ++r)
              if ((dm >> (gl * 16 + quad * 4 + r)) & 1ull) z[r] = -1e30f;
          }
          if (causal) {
            int qcol = qw + qs * 16 + l16;
#pragma unroll
            for (int r = 0; r < 4; ++r)
              if (kw + gl * 16 + quad * 4 + r > qcol) z[r] = -1e30f;
          }
          float e0 = exp2f(z[0]), e1 = exp2f(z[1]);
          float e2 = exp2f(z[2]), e3 = exp2f(z[3]);
          lsum[qs] += (e0 + e1) + (e2 + e3);
          bf16x4 pk = { (bf16_t)e0, (bf16_t)e1, (bf16_t)e2, (bf16_t)e3 };
          *(bf16x4*)&sP[wid][qs][l16 * 72 + gl * 16 + quad * 4] = pk;
        }
      }

      // ctx^T += V^T.P^T (two 32-key chunks of this wave's window)
#pragma unroll
      for (int cp = 0; cp < 2; ++cp) {
        bf16x8 pf0 = *(const bf16x8*)((const bf16_t*)(const void*)&sP[wid][0][0] +
                                      l16 * 72 + cp * 32 + quad * 8);
        bf16x8 pf1 = *(const bf16x8*)((const bf16_t*)(const void*)&sP[wid][1][0] +
                                      l16 * 72 + cp * 32 + quad * 8);
#pragma unroll
        for (int dt = 0; dt < 4; ++dt) {
          bf16x8 vf = *(const bf16x8*)(sV + (dt * 4 + khalf * 2 + cp) * 512 + lane * 8);
          acc[0][dt] = __builtin_amdgcn_mfma_f32_16x16x32_bf16(vf, pf0, acc[0][dt], 0, 0, 0);
          acc[1][dt] = __builtin_amdgcn_mfma_f32_16x16x32_bf16(vf, pf1, acc[1][dt], 0, 0, 0);
        }
      }
    }
  }

  // combine key-half partials (pure sums under fixed-m softmax)
  __syncthreads();                             // sK/sV free now
  float* cacc  = (float*)sKc;                  // 2 x 8KB regions (by qhalf)
  float* clsum = (float*)sVc;
  if (khalf == 1) {
    float* dst = cacc + qhalf * 2048;
#pragma unroll
    for (int qs = 0; qs < 2; ++qs)
#pragma unroll
      for (int dt = 0; dt < 4; ++dt)
        *(f32x4*)(dst + (qs * 4 + dt) * 256 + lane * 4) = acc[qs][dt];
    clsum[qhalf * 128 + lane]      = lsum[0];
    clsum[qhalf * 128 + 64 + lane] = lsum[1];
  }
  __syncthreads();
  if (khalf == 0) {
    const float* src = cacc + qhalf * 2048;
#pragma unroll
    for (int qs = 0; qs < 2; ++qs) {
      lsum[qs] += clsum[qhalf * 128 + qs * 64 + lane];
#pragma unroll
      for (int dt = 0; dt < 4; ++dt)
        acc[qs][dt] += *(const f32x4*)(src + (qs * 4 + dt) * 256 + lane * 4);
    }
    unsigned short* cp2 = (unsigned short*)ctx;
#pragma unroll
    for (int qs = 0; qs < 2; ++qs) {
      float ls = lsum[qs];
      ls += __shfl_xor(ls, 16);
      ls += __shfl_xor(ls, 32);
      float inv = 1.0f / ls;
      size_t trow = ((size_t)(b * S + qw + qs * 16 + l16)) * N + (size_t)(bh & 15) * Dh;
#pragma unroll
      for (int dt = 0; dt < 4; ++dt) {
        u16x4 o = { f2bf(acc[qs][dt][0] * inv), f2bf(acc[qs][dt][1] * inv),
                    f2bf(acc[qs][dt][2] * inv), f2bf(acc[qs][dt][3] * inv) };
        *(u16x4*)&cp2[trow + dt * 16 + quad * 4] = o;
      }
    }
  }
}

// ---------------- launcher ----------------

extern "C" void kernel_launch(void* const* d_in, const int* in_sizes, int n_in,
                              void* d_out, int out_size, void* d_ws, size_t ws_size,
                              hipStream_t stream) {
  const float* x  = (const float*)d_in[0];
  const int*  msk = (const int*)d_in[1];
  const float* Wq = (const float*)d_in[2];
  const float* bq = (const float*)d_in[3];
  const float* Wk = (const float*)d_in[4];
  const float* bk = (const float*)d_in[5];
  const float* Wv = (const float*)d_in[6];
  const float* bv = (const float*)d_in[7];
  const float* Wo = (const float*)d_in[8];
  const float* bo = (const float*)d_in[9];
  float* out = (float*)d_out;
  (void)in_sizes; (void)n_in; (void)out_size; (void)ws_size;

  char* ws = (char*)d_ws;
  bf16_t* xb   = (bf16_t*)(ws);                      // 8 MB  [4096][1024]
  bf16_t* WT   = (bf16_t*)(ws + (8u  << 20));        // 8 MB  4 x [1024][1024] (N-major)
  bf16_t* Qb   = (bf16_t*)(ws + (16u << 20));        // 8 MB  [B,H,S,D]
  bf16_t* Kbuf = (bf16_t*)(ws + (24u << 20));        // 8 MB  [B,H,S,D]
  bf16_t* Vt   = (bf16_t*)(ws + (32u << 20));        // 8 MB  [B,H,D,S] (from gemm_qkv z=2)
  float* ropeC = (float*)(ws + (40u << 20));         // 256 KB
  float* ropeS = ropeC + (size_t)S * 32;             // 256 KB
  bf16_t* ctx  = (bf16_t*)(ws + (41u << 20));        // 8 MB  [B,S,H*D]

  prep_kernel<<<5376, 256, 0, stream>>>(x, xb, Wq, Wk, Wv, Wo, WT, ropeC, ropeS);
  gemm_qkv_kernel<<<dim3(8, 32, 3), 256, 0, stream>>>(xb, WT, bq, bk, bv, Qb, Vt, ropeC, ropeS);
  attn_kernel<<<1024, 256, 0, stream>>>(Qb, Kbuf, Vt, msk, ctx);
  gemm_o_kernel<<<dim3(8, 64), 256, 0, stream>>>(ctx, WT + (size_t)3 * Kd * N, bo, out);
}